// Round 1
// 1426.109 us; speedup vs baseline: 1.0660x; 1.0660x over previous
//
#include <hip/hip_runtime.h>
#include <math.h>

// Problem constants
#define Bn 256
#define Tn 100
#define In 1024
#define Hn 2048
#define On 10
#define Kc (In + Hn)   // 3072 concatenated K

typedef short s8v  __attribute__((ext_vector_type(8)));   // 8 x bf16 (as raw shorts), 4 VGPRs
typedef unsigned short us4 __attribute__((ext_vector_type(4)));
typedef float f32x4 __attribute__((ext_vector_type(4)));

__device__ __forceinline__ unsigned short f2bf(float f) {
    unsigned int u = __float_as_uint(f);
    u += 0x7fffu + ((u >> 16) & 1u);   // round-to-nearest-even
    return (unsigned short)(u >> 16);
}

// Branch-free exact tanh: 1 - 2/(exp(2x)+1). exp overflow -> inf -> rcp -> 0 -> +1;
// exp underflow -> 0 -> rcp(1) -> -1. ~1e-6 abs err, way under bf16 rounding.
__device__ __forceinline__ float fast_tanh(float x) {
    float e = __expf(x + x);
    return 1.0f - 2.0f * __builtin_amdgcn_rcpf(e + 1.0f);
}

// ---- setup kernels -------------------------------------------------------

// x [B][T][I] fp32 -> bf16, 4 elems/thread
__global__ void conv_x_kernel(const float4* __restrict__ src, ushort4* __restrict__ dst) {
    int i = blockIdx.x * 256 + threadIdx.x;
    float4 v = src[i];
    ushort4 o;
    o.x = f2bf(v.x); o.y = f2bf(v.y); o.z = f2bf(v.z); o.w = f2bf(v.w);
    dst[i] = o;
}

// src [K][N=2048] fp32 -> dst[n][colOff + k] bf16  (builds B^T = [Win;W]^T rows)
__global__ void transpose_bf16_kernel(const float* __restrict__ src, unsigned short* __restrict__ dst,
                                      int N, int ld, int colOff) {
    __shared__ float tile[32][33];
    int k0 = blockIdx.x * 32;
    int n0 = blockIdx.y * 32;
    int c = threadIdx.x & 31;
    int r = threadIdx.x >> 5;            // 0..7
    #pragma unroll
    for (int i = 0; i < 32; i += 8)
        tile[r + i][c] = src[(size_t)(k0 + r + i) * N + n0 + c];
    __syncthreads();
    #pragma unroll
    for (int i = 0; i < 32; i += 8)
        dst[(size_t)(n0 + r + i) * ld + colOff + k0 + c] = f2bf(tile[c][r + i]);
}

// h0 -> h_all slot 0 (bf16); lin_w -> padded bf16 [16][2048]; zero barrier block
__global__ void small_conv_kernel(const float* __restrict__ h0, const float* __restrict__ lin_w,
                                  unsigned short* __restrict__ h_all0, unsigned short* __restrict__ lwb,
                                  unsigned int* __restrict__ bar) {
    int idx = blockIdx.x * 256 + threadIdx.x;
    if (idx < 512) bar[idx] = 0u;        // counters + epochs (re-zeroed every launch)
    if (idx < Bn * Hn) {
        h_all0[idx] = f2bf(h0[idx]);
    } else {
        int j = idx - Bn * Hn;           // < 16*2048 exactly (grid sized for it)
        int o = j >> 11;
        int k = j & 2047;
        lwb[j] = (o < On) ? f2bf(lin_w[o * Hn + k]) : (unsigned short)0;
    }
}

// ---- persistent scan -----------------------------------------------------
// 256 blocks x 512 thr (8 waves = 2/SIMD), 1 block/CU. Block tile 64m x 32n;
// n XCD-pinned via blockIdx%8. B-fragments register-resident (R5).
// R6 changes (latency-chain surgery; algorithm/traffic unchanged):
//  * PER-M-GROUP BARRIERS: the 4 m-groups (64 batch rows each) are independent
//    recurrence chains — h rows [m0,m0+64) are produced and consumed only by
//    same-m0 blocks. 4 independent 64-block barriers (counter line + epoch
//    line per group) instead of one 256-block barrier: groups drift freely.
//  * ARRIVAL BEFORE THE x-PART: the barrier-arrival atomic is issued right
//    after the store-drain syncthreads; the cross-barrier x-part pipeline now
//    fills only the POLL window instead of delaying every peer's wakeup.
//  * PER-WAVE POLL, no trailing syncthreads: each wave's lane0 polls the
//    epoch and the wave proceeds to its h-loads immediately (compiler fence
//    after the poll; HW is in-order past the resolved branch).
//  * h-chunk loads explicitly double-buffered (chunk c+1 in flight under
//    chunk c's MFMAs) — trims exposed L3 first-touch latency.
//  * tanh -> branch-free exp2-based fast_tanh on the serial tail.
// Sync (proven R4/R5): relaxed agent-scope write-through h stores; syncthreads
// drains per-wave vmcnt(0) before arrival; fresh h addresses each step make
// plain loads safe (no stale L1/L2 lines possible).
__global__ __launch_bounds__(512, 2)
void scan_kernel(const unsigned short* __restrict__ xb,
                 const unsigned short* __restrict__ BTm,
                 unsigned short* __restrict__ h_all,
                 unsigned int* __restrict__ bar) {
    const int g = blockIdx.x;
    const int mg = (g >> 3) & 3;                        // m-group = independent chain
    const int m0 = mg * 64;
    const int n0 = ((g & 7) * 8 + (g >> 5)) * 32;       // 64 n-tiles, XCD-pinned
    const int w = threadIdx.x >> 6;                     // 0..7
    const int lane = threadIdx.x & 63;
    const int quad = lane >> 4;
    const int lr = lane & 15;

    __shared__ float red[4][64][36];                    // pad 36: 2-way banks (free)

    const unsigned short* bp0 = BTm + (size_t)(n0 + lr) * Kc;
    const unsigned short* bp1 = BTm + (size_t)(n0 + 16 + lr) * Kc;

    const size_t xrow = (size_t)Tn * In;                // x row stride (102400)

    unsigned int* grp_cnt = bar + mg * 32;              // 4 counter lines, 128B apart
    unsigned int* gep     = bar + 128 + mg * 32;        // 4 epoch lines, 128B apart

    // ---- one-time B-fragment preload (lives in registers all 100 steps) ----
    s8v bx[4][2];                                       // x-region B frags
    s8v bh[8][2];                                       // h-region B frags
    #pragma unroll
    for (int c = 0; c < 4; ++c) {
        const int kq = w * 128 + c * 32 + quad * 8;
        bx[c][0] = *(const s8v*)(bp0 + kq);
        bx[c][1] = *(const s8v*)(bp1 + kq);
    }
    #pragma unroll
    for (int c = 0; c < 8; ++c) {
        const int kq = In + w * 256 + c * 32 + quad * 8;
        bh[c][0] = *(const s8v*)(bp0 + kq);
        bh[c][1] = *(const s8v*)(bp1 + kq);
    }

    f32x4 acc[4][2];
    #pragma unroll
    for (int mi = 0; mi < 4; ++mi)
        #pragma unroll
        for (int ni = 0; ni < 2; ++ni)
            acc[mi][ni] = (f32x4){0.f, 0.f, 0.f, 0.f};

    // ---- x-part for t=0 ----
    {
        const unsigned short* xt = xb + 0 * In;
        #pragma unroll
        for (int c = 0; c < 4; ++c) {
            const int kq = w * 128 + c * 32 + quad * 8;
            const unsigned short* arow = xt + kq + (size_t)(m0 + lr) * xrow;
            s8v a0 = *(const s8v*)(arow);
            s8v a1 = *(const s8v*)(arow + 16 * xrow);
            s8v a2 = *(const s8v*)(arow + 32 * xrow);
            s8v a3 = *(const s8v*)(arow + 48 * xrow);
            acc[0][0] = __builtin_amdgcn_mfma_f32_16x16x32_bf16(a0, bx[c][0], acc[0][0], 0, 0, 0);
            acc[1][0] = __builtin_amdgcn_mfma_f32_16x16x32_bf16(a1, bx[c][0], acc[1][0], 0, 0, 0);
            acc[2][0] = __builtin_amdgcn_mfma_f32_16x16x32_bf16(a2, bx[c][0], acc[2][0], 0, 0, 0);
            acc[3][0] = __builtin_amdgcn_mfma_f32_16x16x32_bf16(a3, bx[c][0], acc[3][0], 0, 0, 0);
            acc[0][1] = __builtin_amdgcn_mfma_f32_16x16x32_bf16(a0, bx[c][1], acc[0][1], 0, 0, 0);
            acc[1][1] = __builtin_amdgcn_mfma_f32_16x16x32_bf16(a1, bx[c][1], acc[1][1], 0, 0, 0);
            acc[2][1] = __builtin_amdgcn_mfma_f32_16x16x32_bf16(a2, bx[c][1], acc[2][1], 0, 0, 0);
            acc[3][1] = __builtin_amdgcn_mfma_f32_16x16x32_bf16(a3, bx[c][1], acc[3][1], 0, 0, 0);
        }
    }

    for (int t = 0; t < Tn; ++t) {
        // ---- h-part (gated on the per-wave poll of step t-1) ----
        // double-buffered chunk loads: chunk c+1 issued under chunk c's MFMAs
        const unsigned short* hrow = h_all + (size_t)t * (Bn * Hn)
                                   + (size_t)(m0 + lr) * Hn + w * 256 + quad * 8;
        s8v A[2][4];
        #pragma unroll
        for (int r = 0; r < 4; ++r)
            A[0][r] = *(const s8v*)(hrow + r * 16 * Hn);
        #pragma unroll
        for (int c = 0; c < 8; ++c) {
            if (c < 7) {
                const unsigned short* p = hrow + (c + 1) * 32;
                #pragma unroll
                for (int r = 0; r < 4; ++r)
                    A[(c + 1) & 1][r] = *(const s8v*)(p + r * 16 * Hn);
            }
            const s8v a0 = A[c & 1][0];
            const s8v a1 = A[c & 1][1];
            const s8v a2 = A[c & 1][2];
            const s8v a3 = A[c & 1][3];
            acc[0][0] = __builtin_amdgcn_mfma_f32_16x16x32_bf16(a0, bh[c][0], acc[0][0], 0, 0, 0);
            acc[1][0] = __builtin_amdgcn_mfma_f32_16x16x32_bf16(a1, bh[c][0], acc[1][0], 0, 0, 0);
            acc[2][0] = __builtin_amdgcn_mfma_f32_16x16x32_bf16(a2, bh[c][0], acc[2][0], 0, 0, 0);
            acc[3][0] = __builtin_amdgcn_mfma_f32_16x16x32_bf16(a3, bh[c][0], acc[3][0], 0, 0, 0);
            acc[0][1] = __builtin_amdgcn_mfma_f32_16x16x32_bf16(a0, bh[c][1], acc[0][1], 0, 0, 0);
            acc[1][1] = __builtin_amdgcn_mfma_f32_16x16x32_bf16(a1, bh[c][1], acc[1][1], 0, 0, 0);
            acc[2][1] = __builtin_amdgcn_mfma_f32_16x16x32_bf16(a2, bh[c][1], acc[2][1], 0, 0, 0);
            acc[3][1] = __builtin_amdgcn_mfma_f32_16x16x32_bf16(a3, bh[c][1], acc[3][1], 0, 0, 0);
        }

        // ---- LDS reduce: C/D layout row=quad*4+reg, col=lane&15 [m89/m91] ----
        if (w < 4) {
            #pragma unroll
            for (int mi = 0; mi < 4; ++mi)
                #pragma unroll
                for (int ni = 0; ni < 2; ++ni)
                    #pragma unroll
                    for (int rr = 0; rr < 4; ++rr)
                        red[w][mi * 16 + quad * 4 + rr][ni * 16 + lr] = acc[mi][ni][rr];
        }
        __syncthreads();
        if (w >= 4) {
            #pragma unroll
            for (int mi = 0; mi < 4; ++mi)
                #pragma unroll
                for (int ni = 0; ni < 2; ++ni)
                    #pragma unroll
                    for (int rr = 0; rr < 4; ++rr)
                        red[w - 4][mi * 16 + quad * 4 + rr][ni * 16 + lr] += acc[mi][ni][rr];
        }
        __syncthreads();

        {   // final reduce + tanh + agent-scope write-through store (8 B)
            int j = threadIdx.x << 2;
            int row = j >> 5;
            int c0 = j & 31;
            float4 s0 = *(const float4*)&red[0][row][c0];
            float4 s1 = *(const float4*)&red[1][row][c0];
            float4 s2 = *(const float4*)&red[2][row][c0];
            float4 s3 = *(const float4*)&red[3][row][c0];
            us4 o4;
            o4[0] = f2bf(fast_tanh(s0.x + s1.x + s2.x + s3.x));
            o4[1] = f2bf(fast_tanh(s0.y + s1.y + s2.y + s3.y));
            o4[2] = f2bf(fast_tanh(s0.z + s1.z + s2.z + s3.z));
            o4[3] = f2bf(fast_tanh(s0.w + s1.w + s2.w + s3.w));
            unsigned long long* dst = (unsigned long long*)
                (h_all + (size_t)(t + 1) * (Bn * Hn) + (size_t)(m0 + row) * Hn + n0 + c0);
            __hip_atomic_store(dst, __builtin_bit_cast(unsigned long long, o4),
                               __ATOMIC_RELAXED, __HIP_MEMORY_SCOPE_AGENT);
        }

        if (t < Tn - 1) {
            __syncthreads();                             // per-wave vmcnt(0): h stores drained
            const unsigned int tp1 = (unsigned int)(t + 1);

            // ---- ARRIVE FIRST (off the peers' critical chain) ----
            if (threadIdx.x == 0) {
                unsigned int old = __hip_atomic_fetch_add(grp_cnt, 1u, __ATOMIC_RELAXED,
                                                          __HIP_MEMORY_SCOPE_AGENT);
                if (old == 64u * tp1 - 1u)
                    __hip_atomic_store(gep, tp1, __ATOMIC_RELAXED,
                                       __HIP_MEMORY_SCOPE_AGENT);
            }

            // ---- x-part of t+1 fills the poll window ----
            #pragma unroll
            for (int mi = 0; mi < 4; ++mi)
                #pragma unroll
                for (int ni = 0; ni < 2; ++ni)
                    acc[mi][ni] = (f32x4){0.f, 0.f, 0.f, 0.f};
            const unsigned short* xt = xb + (size_t)(t + 1) * In;
            #pragma unroll
            for (int c = 0; c < 4; ++c) {
                const int kq = w * 128 + c * 32 + quad * 8;
                const unsigned short* arow = xt + kq + (size_t)(m0 + lr) * xrow;
                s8v a0 = *(const s8v*)(arow);
                s8v a1 = *(const s8v*)(arow + 16 * xrow);
                s8v a2 = *(const s8v*)(arow + 32 * xrow);
                s8v a3 = *(const s8v*)(arow + 48 * xrow);
                acc[0][0] = __builtin_amdgcn_mfma_f32_16x16x32_bf16(a0, bx[c][0], acc[0][0], 0, 0, 0);
                acc[1][0] = __builtin_amdgcn_mfma_f32_16x16x32_bf16(a1, bx[c][0], acc[1][0], 0, 0, 0);
                acc[2][0] = __builtin_amdgcn_mfma_f32_16x16x32_bf16(a2, bx[c][0], acc[2][0], 0, 0, 0);
                acc[3][0] = __builtin_amdgcn_mfma_f32_16x16x32_bf16(a3, bx[c][0], acc[3][0], 0, 0, 0);
                acc[0][1] = __builtin_amdgcn_mfma_f32_16x16x32_bf16(a0, bx[c][1], acc[0][1], 0, 0, 0);
                acc[1][1] = __builtin_amdgcn_mfma_f32_16x16x32_bf16(a1, bx[c][1], acc[1][1], 0, 0, 0);
                acc[2][1] = __builtin_amdgcn_mfma_f32_16x16x32_bf16(a2, bx[c][1], acc[2][1], 0, 0, 0);
                acc[3][1] = __builtin_amdgcn_mfma_f32_16x16x32_bf16(a3, bx[c][1], acc[3][1], 0, 0, 0);
            }

            // ---- per-wave poll: wave proceeds the moment its epoch is visible ----
            if (lane == 0) {
                while (__hip_atomic_load(gep, __ATOMIC_RELAXED,
                                         __HIP_MEMORY_SCOPE_AGENT) < tp1)
                    __builtin_amdgcn_s_sleep(2);
            }
            asm volatile("" ::: "memory");               // no load hoisting above the poll
        }
    }
}

// ---- output projection ---------------------------------------------------
// y[b][t][o] = h_all[t+1][b][:] . lin_w[o][:] + lin_b[o]. One 16-row wave per 16 (t,b) rows.
__global__ __launch_bounds__(256)
void gemm2_kernel(const unsigned short* __restrict__ h_all, const unsigned short* __restrict__ lwb,
                  const float* __restrict__ lb, float* __restrict__ y) {
    int gw = blockIdx.x * 4 + (threadIdx.x >> 6);       // 0..1599
    int lane = threadIdx.x & 63, quad = lane >> 4, lr = lane & 15;
    int m0 = gw * 16;
    int t = m0 >> 8;
    int b0 = m0 & 255;
    const unsigned short* ah = h_all + ((size_t)(t + 1) * Bn + b0 + lr) * Hn + quad * 8;
    const unsigned short* bh = lwb + (size_t)lr * Hn + quad * 8;
    f32x4 acc0 = {0.f, 0.f, 0.f, 0.f}, acc1 = {0.f, 0.f, 0.f, 0.f};
    #pragma unroll
    for (int k0 = 0; k0 < Hn; k0 += 64) {
        s8v a0 = *(const s8v*)(ah + k0);
        s8v b0 = *(const s8v*)(bh + k0);
        acc0 = __builtin_amdgcn_mfma_f32_16x16x32_bf16(a0, b0, acc0, 0, 0, 0);
        s8v a1 = *(const s8v*)(ah + k0 + 32);
        s8v b1 = *(const s8v*)(bh + k0 + 32);
        acc1 = __builtin_amdgcn_mfma_f32_16x16x32_bf16(a1, b1, acc1, 0, 0, 0);
    }
    acc0 = acc0 + acc1;
    if (lr < On) {
        float bias = lb[lr];
        #pragma unroll
        for (int rr = 0; rr < 4; ++rr) {
            int b = b0 + quad * 4 + rr;
            y[(size_t)b * (Tn * On) + t * On + lr] = acc0[rr] + bias;
        }
    }
}

// ---- host ----------------------------------------------------------------

extern "C" void kernel_launch(void* const* d_in, const int* in_sizes, int n_in,
                              void* d_out, int out_size, void* d_ws, size_t ws_size,
                              hipStream_t stream) {
    const float* x   = (const float*)d_in[0];
    const float* h0  = (const float*)d_in[1];
    const float* Win = (const float*)d_in[2];
    const float* W   = (const float*)d_in[3];
    const float* lw  = (const float*)d_in[4];
    const float* lb  = (const float*)d_in[5];
    float* y = (float*)d_out;

    // ws layout (bf16 elems): ~171 MB total
    unsigned short* ws    = (unsigned short*)d_ws;
    unsigned short* xb    = ws;                                  // 26,214,400 elems
    unsigned short* BTm   = xb + (size_t)Bn * Tn * In;           //  6,291,456 elems [2048][3072]
    unsigned short* h_all = BTm + (size_t)Hn * Kc;               // 52,953,088 elems [(T+1)][B][H]
    unsigned short* lwb   = h_all + (size_t)(Tn + 1) * Bn * Hn;  //     32,768 elems [16][2048]
    unsigned int*   bar   = (unsigned int*)(lwb + 32768);        // 512 uints barrier block

    conv_x_kernel<<<25600, 256, 0, stream>>>((const float4*)x, (ushort4*)xb);
    transpose_bf16_kernel<<<dim3(32, 64), 256, 0, stream>>>(Win, BTm, Hn, Kc, 0);
    transpose_bf16_kernel<<<dim3(64, 64), 256, 0, stream>>>(W, BTm, Hn, Kc, In);
    small_conv_kernel<<<2176, 256, 0, stream>>>(h0, lw, h_all, lwb, bar);

    scan_kernel<<<256, 512, 0, stream>>>(xb, BTm, h_all, bar);

    gemm2_kernel<<<400, 256, 0, stream>>>(h_all, lwb, lb, y);
}

// Round 3
// 1374.730 us; speedup vs baseline: 1.1058x; 1.0374x over previous
//
#include <hip/hip_runtime.h>
#include <math.h>

// Problem constants
#define Bn 256
#define Tn 100
#define In 1024
#define Hn 2048
#define On 10
#define Kc (In + Hn)   // 3072 concatenated K

typedef short s8v  __attribute__((ext_vector_type(8)));   // 8 x bf16 (as raw shorts), 4 VGPRs
typedef unsigned short us4 __attribute__((ext_vector_type(4)));
typedef float f32x4 __attribute__((ext_vector_type(4)));

__device__ __forceinline__ unsigned short f2bf(float f) {
    unsigned int u = __float_as_uint(f);
    u += 0x7fffu + ((u >> 16) & 1u);   // round-to-nearest-even
    return (unsigned short)(u >> 16);
}

// Branch-free exact tanh: 1 - 2/(exp(2x)+1). exp overflow -> inf -> rcp -> 0 -> +1;
// exp underflow -> 0 -> rcp(1) -> -1. ~1e-6 abs err, way under bf16 rounding.
__device__ __forceinline__ float fast_tanh(float x) {
    float e = __expf(x + x);
    return 1.0f - 2.0f * __builtin_amdgcn_rcpf(e + 1.0f);
}

// ---- setup kernels -------------------------------------------------------

// x [B][T][I] fp32 -> bf16, 4 elems/thread
__global__ void conv_x_kernel(const float4* __restrict__ src, ushort4* __restrict__ dst) {
    int i = blockIdx.x * 256 + threadIdx.x;
    float4 v = src[i];
    ushort4 o;
    o.x = f2bf(v.x); o.y = f2bf(v.y); o.z = f2bf(v.z); o.w = f2bf(v.w);
    dst[i] = o;
}

// src [K][N=2048] fp32 -> dst[n][colOff + k] bf16  (builds B^T = [Win;W]^T rows)
__global__ void transpose_bf16_kernel(const float* __restrict__ src, unsigned short* __restrict__ dst,
                                      int N, int ld, int colOff) {
    __shared__ float tile[32][33];
    int k0 = blockIdx.x * 32;
    int n0 = blockIdx.y * 32;
    int c = threadIdx.x & 31;
    int r = threadIdx.x >> 5;            // 0..7
    #pragma unroll
    for (int i = 0; i < 32; i += 8)
        tile[r + i][c] = src[(size_t)(k0 + r + i) * N + n0 + c];
    __syncthreads();
    #pragma unroll
    for (int i = 0; i < 32; i += 8)
        dst[(size_t)(n0 + r + i) * ld + colOff + k0 + c] = f2bf(tile[c][r + i]);
}

// h0 -> h_all slot 0 (bf16); lin_w -> padded bf16 [16][2048]; zero barrier block
__global__ void small_conv_kernel(const float* __restrict__ h0, const float* __restrict__ lin_w,
                                  unsigned short* __restrict__ h_all0, unsigned short* __restrict__ lwb,
                                  unsigned int* __restrict__ bar) {
    int idx = blockIdx.x * 256 + threadIdx.x;
    if (idx < 512) bar[idx] = 0u;        // per-block flags (re-zeroed every launch)
    if (idx < Bn * Hn) {
        h_all0[idx] = f2bf(h0[idx]);
    } else {
        int j = idx - Bn * Hn;           // < 16*2048 exactly (grid sized for it)
        int o = j >> 11;
        int k = j & 2047;
        lwb[j] = (o < On) ? f2bf(lin_w[o * Hn + k]) : (unsigned short)0;
    }
}

// ---- persistent scan -----------------------------------------------------
// 256 blocks x 512 thr (8 waves = 2/SIMD), 1 block/CU. Block tile 64m x 32n;
// n XCD-pinned via blockIdx%8. B-fragments register-resident (R5).
// R7b (= R7 minus the depth-4 ring, which risked VGPR spill in the K-loop):
//  * FLAG BARRIER, NO COUNTER: the R6 arrival was a 64-way fetch_add to ONE
//    cacheline -> ~64 serialized RMWs per step. Now each block stores its
//    own flag bar[mg*64 + xcd*8 + j] = t+1 (zero contention); consumers
//    poll all 64 group flags with a single 64-lane load + __all. Arrival =
//    one store; detect = one L3 RTT.
//  * 8-SLAB LDS REDUCE: red[8][64][36] (72KB, gfx950 allows 160KB/WG),
//    every wave writes its own slab, ONE __syncthreads, final pass sums 8.
//    Removes one block barrier from the serial tail.
//  * h-load ring kept at depth 2 (A[2][4]) — R6's proven register footprint
//    (84 arch VGPRs; B-frags/acc live in AGPRs, load dests must be VGPRs).
// Sync (proven R4/R5/R6): relaxed agent-scope write-through h stores;
// __syncthreads drains vmcnt(0) (all h stores at coherence point) before the
// flag store; per-wave poll release; fresh h addresses each step make plain
// consumer loads safe (no stale L1/L2 lines possible).
__global__ __launch_bounds__(512, 2)
void scan_kernel(const unsigned short* __restrict__ xb,
                 const unsigned short* __restrict__ BTm,
                 unsigned short* __restrict__ h_all,
                 unsigned int* __restrict__ bar) {
    const int g = blockIdx.x;
    const int mg = (g >> 3) & 3;                        // m-group = independent chain
    const int m0 = mg * 64;
    const int n0 = ((g & 7) * 8 + (g >> 5)) * 32;       // 64 n-tiles, XCD-pinned
    const int w = threadIdx.x >> 6;                     // 0..7
    const int lane = threadIdx.x & 63;
    const int quad = lane >> 4;
    const int lr = lane & 15;

    __shared__ float red[8][64][36];                    // pad 36: 2-way banks (free)

    const unsigned short* bp0 = BTm + (size_t)(n0 + lr) * Kc;
    const unsigned short* bp1 = BTm + (size_t)(n0 + 16 + lr) * Kc;

    const size_t xrow = (size_t)Tn * In;                // x row stride (102400)

    // flag layout: bar[mg*64 + xcd*8 + j]  (g = xcd | mg<<3 | j<<5 bijective)
    const int fidx = mg * 64 + (g & 7) * 8 + (g >> 5);
    unsigned int* fl = bar + mg * 64;                   // my group's 64 flags

    // ---- one-time B-fragment preload (lives in registers all 100 steps) ----
    s8v bx[4][2];                                       // x-region B frags
    s8v bh[8][2];                                       // h-region B frags
    #pragma unroll
    for (int c = 0; c < 4; ++c) {
        const int kq = w * 128 + c * 32 + quad * 8;
        bx[c][0] = *(const s8v*)(bp0 + kq);
        bx[c][1] = *(const s8v*)(bp1 + kq);
    }
    #pragma unroll
    for (int c = 0; c < 8; ++c) {
        const int kq = In + w * 256 + c * 32 + quad * 8;
        bh[c][0] = *(const s8v*)(bp0 + kq);
        bh[c][1] = *(const s8v*)(bp1 + kq);
    }

    f32x4 acc[4][2];
    #pragma unroll
    for (int mi = 0; mi < 4; ++mi)
        #pragma unroll
        for (int ni = 0; ni < 2; ++ni)
            acc[mi][ni] = (f32x4){0.f, 0.f, 0.f, 0.f};

    // ---- x-part for t=0 ----
    {
        const unsigned short* xt = xb + 0 * In;
        #pragma unroll
        for (int c = 0; c < 4; ++c) {
            const int kq = w * 128 + c * 32 + quad * 8;
            const unsigned short* arow = xt + kq + (size_t)(m0 + lr) * xrow;
            s8v a0 = *(const s8v*)(arow);
            s8v a1 = *(const s8v*)(arow + 16 * xrow);
            s8v a2 = *(const s8v*)(arow + 32 * xrow);
            s8v a3 = *(const s8v*)(arow + 48 * xrow);
            acc[0][0] = __builtin_amdgcn_mfma_f32_16x16x32_bf16(a0, bx[c][0], acc[0][0], 0, 0, 0);
            acc[1][0] = __builtin_amdgcn_mfma_f32_16x16x32_bf16(a1, bx[c][0], acc[1][0], 0, 0, 0);
            acc[2][0] = __builtin_amdgcn_mfma_f32_16x16x32_bf16(a2, bx[c][0], acc[2][0], 0, 0, 0);
            acc[3][0] = __builtin_amdgcn_mfma_f32_16x16x32_bf16(a3, bx[c][0], acc[3][0], 0, 0, 0);
            acc[0][1] = __builtin_amdgcn_mfma_f32_16x16x32_bf16(a0, bx[c][1], acc[0][1], 0, 0, 0);
            acc[1][1] = __builtin_amdgcn_mfma_f32_16x16x32_bf16(a1, bx[c][1], acc[1][1], 0, 0, 0);
            acc[2][1] = __builtin_amdgcn_mfma_f32_16x16x32_bf16(a2, bx[c][1], acc[2][1], 0, 0, 0);
            acc[3][1] = __builtin_amdgcn_mfma_f32_16x16x32_bf16(a3, bx[c][1], acc[3][1], 0, 0, 0);
        }
    }

    for (int t = 0; t < Tn; ++t) {
        // ---- h-part (gated on the per-wave poll of step t-1) ----
        // depth-2 ring: chunk c+1 issued under chunk c's MFMAs (proven R6)
        const unsigned short* hrow = h_all + (size_t)t * (Bn * Hn)
                                   + (size_t)(m0 + lr) * Hn + w * 256 + quad * 8;
        s8v A[2][4];
        #pragma unroll
        for (int r = 0; r < 4; ++r)
            A[0][r] = *(const s8v*)(hrow + r * 16 * Hn);
        #pragma unroll
        for (int c = 0; c < 8; ++c) {
            if (c < 7) {
                const unsigned short* p = hrow + (c + 1) * 32;
                #pragma unroll
                for (int r = 0; r < 4; ++r)
                    A[(c + 1) & 1][r] = *(const s8v*)(p + r * 16 * Hn);
            }
            const s8v a0 = A[c & 1][0];
            const s8v a1 = A[c & 1][1];
            const s8v a2 = A[c & 1][2];
            const s8v a3 = A[c & 1][3];
            acc[0][0] = __builtin_amdgcn_mfma_f32_16x16x32_bf16(a0, bh[c][0], acc[0][0], 0, 0, 0);
            acc[1][0] = __builtin_amdgcn_mfma_f32_16x16x32_bf16(a1, bh[c][0], acc[1][0], 0, 0, 0);
            acc[2][0] = __builtin_amdgcn_mfma_f32_16x16x32_bf16(a2, bh[c][0], acc[2][0], 0, 0, 0);
            acc[3][0] = __builtin_amdgcn_mfma_f32_16x16x32_bf16(a3, bh[c][0], acc[3][0], 0, 0, 0);
            acc[0][1] = __builtin_amdgcn_mfma_f32_16x16x32_bf16(a0, bh[c][1], acc[0][1], 0, 0, 0);
            acc[1][1] = __builtin_amdgcn_mfma_f32_16x16x32_bf16(a1, bh[c][1], acc[1][1], 0, 0, 0);
            acc[2][1] = __builtin_amdgcn_mfma_f32_16x16x32_bf16(a2, bh[c][1], acc[2][1], 0, 0, 0);
            acc[3][1] = __builtin_amdgcn_mfma_f32_16x16x32_bf16(a3, bh[c][1], acc[3][1], 0, 0, 0);
        }

        // ---- LDS reduce: C/D layout row=quad*4+reg, col=lane&15 [m89/m91] ----
        // every wave writes its own slab; ONE barrier; final pass sums 8.
        #pragma unroll
        for (int mi = 0; mi < 4; ++mi)
            #pragma unroll
            for (int ni = 0; ni < 2; ++ni)
                #pragma unroll
                for (int rr = 0; rr < 4; ++rr)
                    red[w][mi * 16 + quad * 4 + rr][ni * 16 + lr] = acc[mi][ni][rr];
        __syncthreads();

        {   // final reduce + tanh + agent-scope write-through store (8 B)
            int j = threadIdx.x << 2;
            int row = j >> 5;
            int c0 = j & 31;
            float4 s0 = *(const float4*)&red[0][row][c0];
            float4 s1 = *(const float4*)&red[1][row][c0];
            float4 s2 = *(const float4*)&red[2][row][c0];
            float4 s3 = *(const float4*)&red[3][row][c0];
            float4 s4 = *(const float4*)&red[4][row][c0];
            float4 s5 = *(const float4*)&red[5][row][c0];
            float4 s6 = *(const float4*)&red[6][row][c0];
            float4 s7 = *(const float4*)&red[7][row][c0];
            us4 o4;
            o4[0] = f2bf(fast_tanh(((s0.x + s1.x) + (s2.x + s3.x)) + ((s4.x + s5.x) + (s6.x + s7.x))));
            o4[1] = f2bf(fast_tanh(((s0.y + s1.y) + (s2.y + s3.y)) + ((s4.y + s5.y) + (s6.y + s7.y))));
            o4[2] = f2bf(fast_tanh(((s0.z + s1.z) + (s2.z + s3.z)) + ((s4.z + s5.z) + (s6.z + s7.z))));
            o4[3] = f2bf(fast_tanh(((s0.w + s1.w) + (s2.w + s3.w)) + ((s4.w + s5.w) + (s6.w + s7.w))));
            unsigned long long* dst = (unsigned long long*)
                (h_all + (size_t)(t + 1) * (Bn * Hn) + (size_t)(m0 + row) * Hn + n0 + c0);
            __hip_atomic_store(dst, __builtin_bit_cast(unsigned long long, o4),
                               __ATOMIC_RELAXED, __HIP_MEMORY_SCOPE_AGENT);
        }

        if (t < Tn - 1) {
            __syncthreads();                             // per-wave vmcnt(0): h stores drained
            const unsigned int tp1 = (unsigned int)(t + 1);

            // ---- ARRIVE: one contention-free flag store ----
            if (threadIdx.x == 0)
                __hip_atomic_store(bar + fidx, tp1, __ATOMIC_RELAXED,
                                   __HIP_MEMORY_SCOPE_AGENT);

            // ---- x-part of t+1 fills the poll window ----
            #pragma unroll
            for (int mi = 0; mi < 4; ++mi)
                #pragma unroll
                for (int ni = 0; ni < 2; ++ni)
                    acc[mi][ni] = (f32x4){0.f, 0.f, 0.f, 0.f};
            const unsigned short* xt = xb + (size_t)(t + 1) * In;
            #pragma unroll
            for (int c = 0; c < 4; ++c) {
                const int kq = w * 128 + c * 32 + quad * 8;
                const unsigned short* arow = xt + kq + (size_t)(m0 + lr) * xrow;
                s8v a0 = *(const s8v*)(arow);
                s8v a1 = *(const s8v*)(arow + 16 * xrow);
                s8v a2 = *(const s8v*)(arow + 32 * xrow);
                s8v a3 = *(const s8v*)(arow + 48 * xrow);
                acc[0][0] = __builtin_amdgcn_mfma_f32_16x16x32_bf16(a0, bx[c][0], acc[0][0], 0, 0, 0);
                acc[1][0] = __builtin_amdgcn_mfma_f32_16x16x32_bf16(a1, bx[c][0], acc[1][0], 0, 0, 0);
                acc[2][0] = __builtin_amdgcn_mfma_f32_16x16x32_bf16(a2, bx[c][0], acc[2][0], 0, 0, 0);
                acc[3][0] = __builtin_amdgcn_mfma_f32_16x16x32_bf16(a3, bx[c][0], acc[3][0], 0, 0, 0);
                acc[0][1] = __builtin_amdgcn_mfma_f32_16x16x32_bf16(a0, bx[c][1], acc[0][1], 0, 0, 0);
                acc[1][1] = __builtin_amdgcn_mfma_f32_16x16x32_bf16(a1, bx[c][1], acc[1][1], 0, 0, 0);
                acc[2][1] = __builtin_amdgcn_mfma_f32_16x16x32_bf16(a2, bx[c][1], acc[2][1], 0, 0, 0);
                acc[3][1] = __builtin_amdgcn_mfma_f32_16x16x32_bf16(a3, bx[c][1], acc[3][1], 0, 0, 0);
            }

            // ---- per-wave poll: 64 lanes check 64 group flags in one load ----
            while (true) {
                unsigned int v = __hip_atomic_load(fl + lane, __ATOMIC_RELAXED,
                                                   __HIP_MEMORY_SCOPE_AGENT);
                if (__all((int)(v >= tp1))) break;
                __builtin_amdgcn_s_sleep(1);
            }
            asm volatile("" ::: "memory");               // no load hoisting above the poll
        }
    }
}

// ---- output projection ---------------------------------------------------
// y[b][t][o] = h_all[t+1][b][:] . lin_w[o][:] + lin_b[o]. One 16-row wave per 16 (t,b) rows.
__global__ __launch_bounds__(256)
void gemm2_kernel(const unsigned short* __restrict__ h_all, const unsigned short* __restrict__ lwb,
                  const float* __restrict__ lb, float* __restrict__ y) {
    int gw = blockIdx.x * 4 + (threadIdx.x >> 6);       // 0..1599
    int lane = threadIdx.x & 63, quad = lane >> 4, lr = lane & 15;
    int m0 = gw * 16;
    int t = m0 >> 8;
    int b0 = m0 & 255;
    const unsigned short* ah = h_all + ((size_t)(t + 1) * Bn + b0 + lr) * Hn + quad * 8;
    const unsigned short* bh = lwb + (size_t)lr * Hn + quad * 8;
    f32x4 acc0 = {0.f, 0.f, 0.f, 0.f}, acc1 = {0.f, 0.f, 0.f, 0.f};
    #pragma unroll
    for (int k0 = 0; k0 < Hn; k0 += 64) {
        s8v a0 = *(const s8v*)(ah + k0);
        s8v b0 = *(const s8v*)(bh + k0);
        acc0 = __builtin_amdgcn_mfma_f32_16x16x32_bf16(a0, b0, acc0, 0, 0, 0);
        s8v a1 = *(const s8v*)(ah + k0 + 32);
        s8v b1 = *(const s8v*)(bh + k0 + 32);
        acc1 = __builtin_amdgcn_mfma_f32_16x16x32_bf16(a1, b1, acc1, 0, 0, 0);
    }
    acc0 = acc0 + acc1;
    if (lr < On) {
        float bias = lb[lr];
        #pragma unroll
        for (int rr = 0; rr < 4; ++rr) {
            int b = b0 + quad * 4 + rr;
            y[(size_t)b * (Tn * On) + t * On + lr] = acc0[rr] + bias;
        }
    }
}

// ---- host ----------------------------------------------------------------

extern "C" void kernel_launch(void* const* d_in, const int* in_sizes, int n_in,
                              void* d_out, int out_size, void* d_ws, size_t ws_size,
                              hipStream_t stream) {
    const float* x   = (const float*)d_in[0];
    const float* h0  = (const float*)d_in[1];
    const float* Win = (const float*)d_in[2];
    const float* W   = (const float*)d_in[3];
    const float* lw  = (const float*)d_in[4];
    const float* lb  = (const float*)d_in[5];
    float* y = (float*)d_out;

    // ws layout (bf16 elems): ~171 MB total
    unsigned short* ws    = (unsigned short*)d_ws;
    unsigned short* xb    = ws;                                  // 26,214,400 elems
    unsigned short* BTm   = xb + (size_t)Bn * Tn * In;           //  6,291,456 elems [2048][3072]
    unsigned short* h_all = BTm + (size_t)Hn * Kc;               // 52,953,088 elems [(T+1)][B][H]
    unsigned short* lwb   = h_all + (size_t)(Tn + 1) * Bn * Hn;  //     32,768 elems [16][2048]
    unsigned int*   bar   = (unsigned int*)(lwb + 32768);        // 512 uints flag block

    conv_x_kernel<<<25600, 256, 0, stream>>>((const float4*)x, (ushort4*)xb);
    transpose_bf16_kernel<<<dim3(32, 64), 256, 0, stream>>>(Win, BTm, Hn, Kc, 0);
    transpose_bf16_kernel<<<dim3(64, 64), 256, 0, stream>>>(W, BTm, Hn, Kc, In);
    small_conv_kernel<<<2176, 256, 0, stream>>>(h0, lw, h_all, lwb, bar);

    scan_kernel<<<256, 512, 0, stream>>>(xb, BTm, h_all, bar);

    gemm2_kernel<<<400, 256, 0, stream>>>(h_all, lwb, lb, y);
}